// Round 1
// baseline (1328.511 us; speedup 1.0000x reference)
//
#include <hip/hip_runtime.h>
#include <hip/hip_bf16.h>
#include <math.h>

// MoEGate: scores = sigmoid(x @ W^T); group top-2-sum -> top-4 groups -> top-8
// experts -> normalized weights * 2.5.
// Phase 1: fp32 vector GEMM (no fp32 MFMA on CDNA4), K-split=2, partials in ws.
// Phase 2: fused reduce + sigmoid + routing, 1 thread/token, LDS row scratch.

constexpr int T_TOK = 8192;
constexpr int HID   = 7168;
constexpr int NEXP  = 256;

constexpr int BM = 64, BN = 64, BK = 32;
constexpr int KSPLIT = 2;
constexpr int KHALF  = HID / KSPLIT;   // 3584, 112 K-tiles of 32
constexpr int LDS4   = 9;              // float4 stride per row (8 data + 1 pad)

__global__ __launch_bounds__(64)
void gemm_partial(const float* __restrict__ x, const float* __restrict__ w,
                  float* __restrict__ part) {
  __shared__ float4 As4[BM * LDS4];   // [token_row][k/4] padded
  __shared__ float4 Bs4[BN * LDS4];   // [expert_row][k/4] padded
  const int lane = threadIdx.x;
  const int e0 = blockIdx.x * BN;     // expert tile (fastest -> x reuse in L2/L3)
  const int t0 = blockIdx.y * BM;     // token tile
  const int kp = blockIdx.z;          // k-split half
  const size_t kbase = (size_t)kp * KHALF;

  const int tx = lane & 7;            // expert sub / staging col4
  const int ty = lane >> 3;           // token sub  / staging row base

  float acc[8][8];
#pragma unroll
  for (int i = 0; i < 8; ++i)
#pragma unroll
    for (int j = 0; j < 8; ++j) acc[i][j] = 0.f;

  // staging base pointers: thread stages rows (ty + 8p), float4 column tx
  const float* xs = x + (size_t)(t0 + ty) * HID + kbase + 4 * tx;
  const float* wsrc = w + (size_t)(e0 + ty) * HID + kbase + 4 * tx;

  float4 pa[8], pb[8];
#pragma unroll
  for (int p = 0; p < 8; ++p) {
    pa[p] = *(const float4*)(xs + (size_t)(8 * p) * HID);
    pb[p] = *(const float4*)(wsrc + (size_t)(8 * p) * HID);
  }

  for (int k0 = 0; k0 < KHALF; k0 += BK) {
    __syncthreads();
#pragma unroll
    for (int p = 0; p < 8; ++p) {
      As4[(ty + 8 * p) * LDS4 + tx] = pa[p];
      Bs4[(ty + 8 * p) * LDS4 + tx] = pb[p];
    }
    __syncthreads();
    if (k0 + BK < KHALF) {
#pragma unroll
      for (int p = 0; p < 8; ++p) {
        pa[p] = *(const float4*)(xs + (size_t)(8 * p) * HID + (k0 + BK));
        pb[p] = *(const float4*)(wsrc + (size_t)(8 * p) * HID + (k0 + BK));
      }
    }
#pragma unroll
    for (int q = 0; q < 8; ++q) {     // 4 k's per step
      float4 av[8], bv[8];
#pragma unroll
      for (int i = 0; i < 8; ++i) av[i] = As4[(ty + 8 * i) * LDS4 + q];
#pragma unroll
      for (int j = 0; j < 8; ++j) bv[j] = Bs4[(tx + 8 * j) * LDS4 + q];
#pragma unroll
      for (int i = 0; i < 8; ++i)
#pragma unroll
        for (int j = 0; j < 8; ++j) {
          acc[i][j] += av[i].x * bv[j].x;
          acc[i][j] += av[i].y * bv[j].y;
          acc[i][j] += av[i].z * bv[j].z;
          acc[i][j] += av[i].w * bv[j].w;
        }
    }
  }

  float* pout = part + (size_t)kp * T_TOK * NEXP;
#pragma unroll
  for (int i = 0; i < 8; ++i) {
    const size_t t = t0 + ty + 8 * i;
#pragma unroll
    for (int j = 0; j < 8; ++j)
      pout[t * NEXP + (e0 + tx + 8 * j)] = acc[i][j];
  }
}

__global__ __launch_bounds__(64)
void routing_kernel(const float* __restrict__ part,
                    const float* __restrict__ bias,
                    float* __restrict__ out) {
  // 64 tokens/block; each thread owns one token, scores row in LDS scratch.
  // XOR swizzle on low 5 bits of column -> conflict-free per-lane access.
  __shared__ float tile[64][256];     // exactly 64 KB
  const int lane = threadIdx.x;
  const int t = blockIdx.x * 64 + lane;
  const int sw = lane & 31;

  const float* p0 = part + (size_t)t * NEXP;
  const float* p1 = p0 + (size_t)T_TOK * NEXP;
#pragma unroll 8
  for (int c = 0; c < NEXP; c += 4) {
    float4 a = *(const float4*)(p0 + c);
    float4 b = *(const float4*)(p1 + c);
    tile[lane][(c + 0) ^ sw] = 1.f / (1.f + expf(-(a.x + b.x)));
    tile[lane][(c + 1) ^ sw] = 1.f / (1.f + expf(-(a.y + b.y)));
    tile[lane][(c + 2) ^ sw] = 1.f / (1.f + expf(-(a.z + b.z)));
    tile[lane][(c + 3) ^ sw] = 1.f / (1.f + expf(-(a.w + b.w)));
  }
  // no barrier needed: each lane reads only its own row

  // group scores: sum of top-2 of (score + bias) within each group of 32
  float gsum[8];
#pragma unroll
  for (int g = 0; g < 8; ++g) {
    float m1 = -3.4e38f, m2 = -3.4e38f;
    for (int j = 0; j < 32; ++j) {
      const int e = g * 32 + j;
      const float s = tile[lane][e ^ sw] + bias[e];
      const float nm1 = fmaxf(m1, s);
      m2 = fmaxf(m2, fminf(m1, s));
      m1 = nm1;
    }
    gsum[g] = m1 + m2;
  }

  // stable top-4 groups (strict >, ascending scan = lowest index on ties)
  unsigned gmask = 0;
#pragma unroll
  for (int r = 0; r < 4; ++r) {
    int best = 0; float bv = -3.4e38f;
#pragma unroll
    for (int g = 0; g < 8; ++g) {
      const bool ok = (((gmask >> g) & 1u) == 0) && (gsum[g] > bv);
      bv = ok ? gsum[g] : bv;
      best = ok ? g : best;
    }
    gmask |= 1u << best;
  }

  // stable descending top-8 over selected groups (branchless ordered insert,
  // all register-resident; ties keep earlier expert first = lax.top_k order)
  float val[8]; int idx[8];
#pragma unroll
  for (int i = 0; i < 8; ++i) { val[i] = -3.4e38f; idx[i] = 0; }

  for (int g = 0; g < 8; ++g) {
    if (!((gmask >> g) & 1u)) continue;
    for (int j = 0; j < 32; ++j) {
      const int e = g * 32 + j;
      const float s = tile[lane][e ^ sw] + bias[e];
      if (s > val[7]) {
#pragma unroll
        for (int p = 7; p >= 1; --p) {
          const bool cp  = s > val[p];
          const bool cpm = s > val[p - 1];
          const float nv = cp ? (cpm ? val[p - 1] : s) : val[p];
          const int  ni  = cp ? (cpm ? idx[p - 1] : e) : idx[p];
          val[p] = nv; idx[p] = ni;
        }
        const bool c0 = s > val[0];
        val[0] = c0 ? s : val[0];
        idx[0] = c0 ? e : idx[0];
      }
    }
  }

  // weights from ORIGINAL scores (no bias), normalize, scale
  float worig[8];
  float wsum = 1e-20f;
#pragma unroll
  for (int i = 0; i < 8; ++i) { worig[i] = tile[lane][idx[i] ^ sw]; wsum += worig[i]; }
  const float scale = 2.5f / wsum;
#pragma unroll
  for (int i = 0; i < 8; ++i) out[(size_t)t * 8 + i] = worig[i] * scale;
  float* oidx = out + (size_t)T_TOK * 8;
#pragma unroll
  for (int i = 0; i < 8; ++i) oidx[(size_t)t * 8 + i] = (float)idx[i];
}

extern "C" void kernel_launch(void* const* d_in, const int* in_sizes, int n_in,
                              void* d_out, int out_size, void* d_ws, size_t ws_size,
                              hipStream_t stream) {
  const float* x    = (const float*)d_in[0];
  const float* w    = (const float*)d_in[1];
  const float* bias = (const float*)d_in[2];
  float* out  = (float*)d_out;
  float* part = (float*)d_ws;   // [KSPLIT][T_TOK][NEXP] fp32 = 16 MB

  dim3 ggrid(NEXP / BN, T_TOK / BM, KSPLIT);   // (4, 128, 2) = 1024 blocks
  hipLaunchKernelGGL(gemm_partial, ggrid, dim3(64), 0, stream, x, w, part);
  hipLaunchKernelGGL(routing_kernel, dim3(T_TOK / 64), dim3(64), 0, stream,
                     part, bias, out);
}